// Round 15
// baseline (263.236 us; speedup 1.0000x reference)
//
#include <hip/hip_runtime.h>
#include <hip/hip_bf16.h>
#include <hip/hip_fp16.h>

typedef __attribute__((ext_vector_type(8))) short short8;
typedef __attribute__((ext_vector_type(4))) float f32x4;
typedef __attribute__((ext_vector_type(4))) float floatv4;

// Problem constants (from reference)
constexpr int NN = 50000;   // nodes
constexpr int NE = 800000;  // edges
constexpr int FN = 64;      // node feat
constexpr int FE = 32;      // edge feat
constexpr int FG = 32;      // global feat
constexpr int OD = 64;      // out dim
constexpr int NG = 256;     // graphs

constexpr int NWIN_E = NE / 16;                         // 50000 edge windows
constexpr int MS_BLOCKS = 2048;
constexpr int MS_WAVES  = MS_BLOCKS * 4;

constexpr int XCVT_BLOCKS = (NN * FN / 8 + 255) / 256;  // 1563
constexpr int UW2_BLOCKS  = (NG * 64) / 256;            // 64
constexpr int HIST_BLOCKS = (NE + 255) / 256;           // 3125
constexpr int PRE_BLOCKS  = XCVT_BLOCKS + UW2_BLOCKS + HIST_BLOCKS;

constexpr int SCAN_T   = 1024;
constexpr int SCAN_PER = (NN + SCAN_T - 1) / SCAN_T;    // 49

constexpr int NWIN_N = NN / 16;                         // 3125
constexpr int NODE_BLOCKS = 782;                        // 1 window per wave
constexpr int NODE_WAVES  = NODE_BLOCKS * 4;

static __device__ __forceinline__ unsigned pack_bf16(float a, float b) {
    __hip_bfloat162 h = __float22bfloat162_rn(float2{a, b});
    return *reinterpret_cast<unsigned*>(&h);
}

// ---------------------------------------------------------------------------
// Fused precompute + histogram (one grid, three block ranges):
//   [0, XCVT)           : x -> bf16 table
//   [XCVT, XCVT+64)     : uW2b = b2 + u@W2_u (exact f32)
//   [XCVT+64, ...)      : dst histogram (cnt pre-zeroed by memset)
// ---------------------------------------------------------------------------
__global__ __launch_bounds__(256) void k_pre(const float* __restrict__ x,
                                             unsigned* __restrict__ xb32,
                                             const float* __restrict__ u,
                                             const float* __restrict__ W2,
                                             const float* __restrict__ b2,
                                             float* __restrict__ uW2b,
                                             const int* __restrict__ ei,
                                             int* __restrict__ cnt) {
    if (blockIdx.x >= XCVT_BLOCKS + UW2_BLOCKS) {  // histogram part
        const int e = (blockIdx.x - XCVT_BLOCKS - UW2_BLOCKS) * 256 + threadIdx.x;
        if (e < NE) atomicAdd(&cnt[ei[e]], 1);
        return;
    }
    if (blockIdx.x >= XCVT_BLOCKS) {  // uW2b part
        const int lane = threadIdx.x & 63;
        float wcol[FG];
#pragma unroll
        for (int k = 0; k < FG; ++k) wcol[k] = W2[(FN + OD + k) * OD + lane];
        const float bias = b2[lane];
        int g = ((blockIdx.x - XCVT_BLOCKS) * 256 + threadIdx.x) >> 6;
        g = __builtin_amdgcn_readfirstlane(g);
        if (g >= NG) return;
        const float* __restrict__ urow = u + (size_t)g * FG;
        float acc = bias;
#pragma unroll
        for (int k = 0; k < FG; ++k) acc = fmaf(urow[k], wcol[k], acc);
        uW2b[(size_t)g * OD + lane] = acc;
        return;
    }
    const int i = blockIdx.x * 256 + threadIdx.x;
    if (i >= NN * FN / 8) return;
    const float4* p = (const float4*)(x + (size_t)i * 8);
    float4 f0 = p[0], f1 = p[1];
    uint4 o;
    o.x = pack_bf16(f0.x, f0.y);
    o.y = pack_bf16(f0.z, f0.w);
    o.z = pack_bf16(f1.x, f1.y);
    o.w = pack_bf16(f1.z, f1.w);
    ((uint4*)xb32)[i] = o;
}

// ---------------------------------------------------------------------------
// Single-dispatch exclusive scan: one block, 1024 threads, 49 counts each.
// Pass 1: serial sum -> block Hillis-Steele scan -> pass 2: write prefixes.
// ---------------------------------------------------------------------------
__global__ __launch_bounds__(SCAN_T) void k_scan(const int* __restrict__ cnt,
                                                 int* __restrict__ start,
                                                 int* __restrict__ cursor) {
    __shared__ int lds[SCAN_T];
    const int t = threadIdx.x;
    const int i0 = t * SCAN_PER;
    const int i1 = (i0 + SCAN_PER < NN) ? (i0 + SCAN_PER) : NN;

    int s = 0;
    for (int i = i0; i < i1; ++i) s += cnt[i];
    lds[t] = s;
    __syncthreads();
#pragma unroll
    for (int off = 1; off < SCAN_T; off <<= 1) {
        int v = (t >= off) ? lds[t - off] : 0;
        __syncthreads();
        lds[t] += v;
        __syncthreads();
    }
    const int excl = lds[t] - s;
    if (t == SCAN_T - 1) start[NN] = lds[t];  // grand total == NE

    int run = excl;
    for (int i = i0; i < i1; ++i) {
        const int v = cnt[i];
        start[i] = run;
        cursor[i] = run;
        run += v;
    }
}

// ---------------------------------------------------------------------------
// Edge-major message computation + scatter (the ONE permutation pass).
// ei/ea loaded NONTEMPORAL (stream-once; keeps L2 for cursor/mbuf lines);
// mbuf stored NORMALLY (r13 lesson: NT stores evict the producer->consumer
// buffer from L2 and cost nodem2 ~25 us).
//   window = 16 consecutive edges; msg = relu([x_bf16[src] | ea] @ W1 + b1)
//   slot = atomic cursor[dst]; store msg row as f16 into mbuf[slot]
//   (column-permuted storage: f16 index slot*64 + c*4 + b holds col c+16b).
// Fragment layouts (mfma_f32_16x16x32_bf16), verified rounds 2-13:
//   A: row = lane&15, k = 8*(lane>>4)+i ; B: col = lane&15, same k
//   C: col = lane&15, row = (lane>>4)*4 + q
// ---------------------------------------------------------------------------
__global__ __launch_bounds__(256) void k_msgscat(const int* __restrict__ ei,
                                                 const float* __restrict__ ea,
                                                 const unsigned short* __restrict__ xb,
                                                 const float* __restrict__ W1,
                                                 const float* __restrict__ b1,
                                                 int* __restrict__ cursor,
                                                 unsigned short* __restrict__ mbuf) {
    const int l = threadIdx.x & 63;
    const int g = l >> 4;
    const int c = l & 15;

    // W1 B-fragments: wf[t][b] covers k = 32t.., cols 16b..16b+15
    short8 wf[3][4];
#pragma unroll
    for (int t = 0; t < 3; ++t)
#pragma unroll
        for (int b = 0; b < 4; ++b)
#pragma unroll
            for (int i = 0; i < 8; i += 2) {
                const int k = 32 * t + 8 * g + i;
                const unsigned p = pack_bf16(W1[k * OD + (c + 16 * b)],
                                             W1[(k + 1) * OD + (c + 16 * b)]);
                ((unsigned*)&wf[t][b])[i / 2] = p;
            }
    float bias[4];
#pragma unroll
    for (int b = 0; b < 4; ++b) bias[b] = b1[c + 16 * b];

    int wv = (blockIdx.x * blockDim.x + threadIdx.x) >> 6;
    wv = __builtin_amdgcn_readfirstlane(wv);

    for (int w = wv; w < NWIN_E; w += MS_WAVES) {
        const int e = w * 16 + c;            // this lane's edge (dup over g)
        const int dst = __builtin_nontemporal_load(&ei[e]);       // coalesced
        const int src = __builtin_nontemporal_load(&ei[NE + e]);  // coalesced
        int pos = 0;
        if (l < 16) pos = atomicAdd(&cursor[dst], 1);

        // A fragments: chunks 0,1 = x_bf16[src] (gather), chunk 2 = cvt(ea[e])
        short8 a0, a1, a2;
        {
            const uint4* xr = (const uint4*)(xb + (size_t)src * FN);
            uint4 q0 = xr[g];
            uint4 q1 = xr[4 + g];
            a0 = *(short8*)&q0;
            a1 = *(short8*)&q1;
        }
        {
            const floatv4* er = (const floatv4*)(ea + (size_t)e * FE);  // coalesced
            floatv4 e0 = __builtin_nontemporal_load(&er[2 * g]);
            floatv4 e1 = __builtin_nontemporal_load(&er[2 * g + 1]);
            uint4 q2;
            q2.x = pack_bf16(e0.x, e0.y);
            q2.y = pack_bf16(e0.z, e0.w);
            q2.z = pack_bf16(e1.x, e1.y);
            q2.w = pack_bf16(e1.z, e1.w);
            a2 = *(short8*)&q2;
        }

        f32x4 accb[4];
#pragma unroll
        for (int b = 0; b < 4; ++b) {
            f32x4 acc = {0.f, 0.f, 0.f, 0.f};
            acc = __builtin_amdgcn_mfma_f32_16x16x32_bf16(a0, wf[0][b], acc, 0, 0, 0);
            acc = __builtin_amdgcn_mfma_f32_16x16x32_bf16(a1, wf[1][b], acc, 0, 0, 0);
            acc = __builtin_amdgcn_mfma_f32_16x16x32_bf16(a2, wf[2][b], acc, 0, 0, 0);
            accb[b] = acc;
        }

        // store: row r = 4g+q belongs to edge w*16+r; its slot came from lane r
#pragma unroll
        for (int q = 0; q < 4; ++q) {
            const int pr = __shfl(pos, 4 * g + q);  // slot of edge 4g+q
            const float v0 = fmaxf(accb[0][q] + bias[0], 0.0f);
            const float v1 = fmaxf(accb[1][q] + bias[1], 0.0f);
            const float v2 = fmaxf(accb[2][q] + bias[2], 0.0f);
            const float v3 = fmaxf(accb[3][q] + bias[3], 0.0f);
            const __half2 h01 = __float22half2_rn(float2{v0, v1});
            const __half2 h23 = __float22half2_rn(float2{v2, v3});
            uint2 outv;
            outv.x = *reinterpret_cast<const unsigned*>(&h01);
            outv.y = *reinterpret_cast<const unsigned*>(&h23);
            *reinterpret_cast<uint2*>(mbuf + (size_t)pr * 64 + c * 4) = outv;
        }
    }
}

// ---------------------------------------------------------------------------
// Fused segment-reduce + node MLP (r11 verbatim):
//   wave owns 16 consecutive nodes. Lane (g,c) sums node (n0+c)'s mbuf rows
//   (dst-sorted contiguous segment) over STORED chunks, f32 accumulate, then
//   packs to bf16 A-fragments and runs the node MFMA with W2 rows permuted
//   to match storage order: stored s -> true col (s>>2) + 16*(s&3).
//   out = relu([x_bf16 | agg] @ W2[0:128] + uW2b[batch])
// ---------------------------------------------------------------------------
__global__ __launch_bounds__(256) void k_nodem2(const unsigned short* __restrict__ xb,
                                                const unsigned short* __restrict__ mbuf,
                                                const int* __restrict__ start,
                                                const int* __restrict__ bat,
                                                const float* __restrict__ uW2b,
                                                const float* __restrict__ W2,
                                                float* __restrict__ out) {
    const int l = threadIdx.x & 63;
    const int g = l >> 4;
    const int c = l & 15;

    // W2 B-fragments; t>=2 rows permuted to storage order (verified r7/r11)
    short8 wf[4][4];
#pragma unroll
    for (int t = 0; t < 4; ++t)
#pragma unroll
        for (int b = 0; b < 4; ++b)
#pragma unroll
            for (int i = 0; i < 8; i += 2) {
                const int col = c + 16 * b;
                unsigned p;
                if (t < 2) {
                    const int k = 32 * t + 8 * g + i;
                    p = pack_bf16(W2[k * OD + col], W2[(k + 1) * OD + col]);
                } else {
                    const int sc0 = 32 * (t - 2) + 8 * g + i;
                    const int sc1 = sc0 + 1;
                    const int k0 = FN + ((sc0 >> 2) + 16 * (sc0 & 3));
                    const int k1 = FN + ((sc1 >> 2) + 16 * (sc1 & 3));
                    p = pack_bf16(W2[k0 * OD + col], W2[k1 * OD + col]);
                }
                ((unsigned*)&wf[t][b])[i / 2] = p;
            }

    int wv = (blockIdx.x * blockDim.x + threadIdx.x) >> 6;
    wv = __builtin_amdgcn_readfirstlane(wv);

    for (int w = wv; w < NWIN_N; w += NODE_WAVES) {
        const int n0 = w * 16;
        const int n = n0 + c;
        const int s0 = start[n];
        const int cntn = start[n + 1] - s0;

        // wave-max segment length over the 16 nodes
        int mc = cntn;
        mc = max(mc, __shfl_xor(mc, 1));
        mc = max(mc, __shfl_xor(mc, 2));
        mc = max(mc, __shfl_xor(mc, 4));
        mc = max(mc, __shfl_xor(mc, 8));

        // segment sum in f32, stored-order chunks
        float s2v[8] = {0, 0, 0, 0, 0, 0, 0, 0};
        float s3v[8] = {0, 0, 0, 0, 0, 0, 0, 0};
        const unsigned short* rowb = mbuf + (size_t)s0 * 64 + 8 * g;
        for (int i = 0; i < mc; ++i) {
            if (i < cntn) {
                const uint4 u2 = *(const uint4*)(rowb + (size_t)i * 64);
                const uint4 u3 = *(const uint4*)(rowb + (size_t)i * 64 + 32);
                const __half2* h2 = (const __half2*)&u2;
                const __half2* h3 = (const __half2*)&u3;
#pragma unroll
                for (int j = 0; j < 4; ++j) {
                    const float2 f2 = __half22float2(h2[j]);
                    const float2 f3 = __half22float2(h3[j]);
                    s2v[2 * j]     += f2.x;
                    s2v[2 * j + 1] += f2.y;
                    s3v[2 * j]     += f3.x;
                    s3v[2 * j + 1] += f3.y;
                }
            }
        }
        uint4 qa2, qa3;
        qa2.x = pack_bf16(s2v[0], s2v[1]);
        qa2.y = pack_bf16(s2v[2], s2v[3]);
        qa2.z = pack_bf16(s2v[4], s2v[5]);
        qa2.w = pack_bf16(s2v[6], s2v[7]);
        qa3.x = pack_bf16(s3v[0], s3v[1]);
        qa3.y = pack_bf16(s3v[2], s3v[3]);
        qa3.z = pack_bf16(s3v[4], s3v[5]);
        qa3.w = pack_bf16(s3v[6], s3v[7]);

        // x A-fragments (coalesced: consecutive node rows)
        const uint4* xr = (const uint4*)(xb + (size_t)n * FN);
        uint4 qx0 = xr[g], qx1 = xr[4 + g];
        short8 a0 = *(short8*)&qx0, a1 = *(short8*)&qx1;
        short8 a2 = *(short8*)&qa2, a3 = *(short8*)&qa3;

        int bq[4];
#pragma unroll
        for (int q = 0; q < 4; ++q) bq[q] = bat[n0 + g * 4 + q];

#pragma unroll
        for (int b = 0; b < 4; ++b) {
            f32x4 acc = {0.f, 0.f, 0.f, 0.f};
            acc = __builtin_amdgcn_mfma_f32_16x16x32_bf16(a0, wf[0][b], acc, 0, 0, 0);
            acc = __builtin_amdgcn_mfma_f32_16x16x32_bf16(a1, wf[1][b], acc, 0, 0, 0);
            acc = __builtin_amdgcn_mfma_f32_16x16x32_bf16(a2, wf[2][b], acc, 0, 0, 0);
            acc = __builtin_amdgcn_mfma_f32_16x16x32_bf16(a3, wf[3][b], acc, 0, 0, 0);
#pragma unroll
            for (int q = 0; q < 4; ++q) {
                const int nn = n0 + g * 4 + q;
                const float val = acc[q] + uW2b[(size_t)bq[q] * OD + c + 16 * b];
                out[(size_t)nn * OD + c + 16 * b] = fmaxf(val, 0.0f);
            }
        }
    }
}

// ---------------------------------------------------------------------------
extern "C" void kernel_launch(void* const* d_in, const int* in_sizes, int n_in,
                              void* d_out, int out_size, void* d_ws, size_t ws_size,
                              hipStream_t stream) {
    const float* x    = (const float*)d_in[0];   // (50000, 64)
    const int*   ei   = (const int*)d_in[1];     // (2, 800000)
    const float* ea   = (const float*)d_in[2];   // (800000, 32)
    const float* u    = (const float*)d_in[3];   // (256, 32)
    const int*   bat  = (const int*)d_in[4];     // (50000,)
    const float* W1   = (const float*)d_in[5];   // (96, 64)
    const float* b1   = (const float*)d_in[6];   // (64,)
    const float* W2   = (const float*)d_in[7];   // (160, 64)
    const float* b2   = (const float*)d_in[8];   // (64,)
    float* out = (float*)d_out;                  // (50000, 64)

    // workspace layout (~110 MB; mbuf dominates)
    char* ws = (char*)d_ws;
    auto alloc = [&](size_t bytes) {
        char* p = ws;
        ws += (bytes + 255) & ~size_t(255);
        return p;
    };
    unsigned short* xb = (unsigned short*)alloc((size_t)NN * FN * 2);     // 6.4 MB
    float* uW2b    = (float*)alloc((size_t)NG * OD * sizeof(float));
    int*   cnt     = (int*)alloc((size_t)NN * sizeof(int));
    int*   start   = (int*)alloc((size_t)(NN + 1) * sizeof(int));
    int*   cursor  = (int*)alloc((size_t)NN * sizeof(int));
    unsigned short* mbuf = (unsigned short*)alloc((size_t)NE * OD * 2);   // 102.4 MB

    // zero histogram counters (stream-ordered before k_pre's hist blocks)
    hipMemsetAsync(cnt, 0, (size_t)NN * sizeof(int), stream);

    // fused precompute (x->bf16, uW2b) + dst histogram, one grid
    k_pre<<<dim3(PRE_BLOCKS), dim3(256), 0, stream>>>(x, (unsigned*)xb, u, W2, b2,
                                                      uW2b, ei, cnt);

    // single-dispatch exclusive scan
    k_scan<<<dim3(1), dim3(SCAN_T), 0, stream>>>(cnt, start, cursor);

    // the one permutation pass: edge-major MFMA messages -> dst-sorted slots
    k_msgscat<<<dim3(MS_BLOCKS), dim3(256), 0, stream>>>(ei, ea, xb, W1, b1, cursor, mbuf);

    // fused segment-reduce + node MLP
    k_nodem2<<<dim3(NODE_BLOCKS), dim3(256), 0, stream>>>(xb, mbuf, start, bat, uW2b, W2, out);
}

// Round 16
// 159.910 us; speedup vs baseline: 1.6462x; 1.6462x over previous
//
#include <hip/hip_runtime.h>
#include <hip/hip_bf16.h>
#include <hip/hip_fp16.h>

typedef __attribute__((ext_vector_type(8))) short short8;
typedef __attribute__((ext_vector_type(4))) float f32x4;
typedef __attribute__((ext_vector_type(4))) float floatv4;

// Problem constants (from reference)
constexpr int NN = 50000;   // nodes
constexpr int NE = 800000;  // edges
constexpr int FN = 64;      // node feat
constexpr int FE = 32;      // edge feat
constexpr int FG = 32;      // global feat
constexpr int OD = 64;      // out dim
constexpr int NG = 256;     // graphs

constexpr int SCAN_B = 256;
constexpr int NBLK = (NN + SCAN_B - 1) / SCAN_B;        // 196

constexpr int NWIN_E = NE / 16;                         // 50000 edge windows
constexpr int MS_BLOCKS = 2048;
constexpr int MS_WAVES  = MS_BLOCKS * 4;

constexpr int XCVT_BLOCKS = (NN * FN / 8 + 255) / 256;  // 1563
constexpr int UW2_BLOCKS  = (NG * 64) / 256;            // 64
constexpr int HIST_BLOCKS = (NE + 255) / 256;           // 3125
constexpr int PRE_BLOCKS  = XCVT_BLOCKS + UW2_BLOCKS + HIST_BLOCKS;

constexpr int NWIN_N = NN / 16;                         // 3125
constexpr int NODE_BLOCKS = 782;                        // 1 window per wave
constexpr int NODE_WAVES  = NODE_BLOCKS * 4;

static __device__ __forceinline__ unsigned pack_bf16(float a, float b) {
    __hip_bfloat162 h = __float22bfloat162_rn(float2{a, b});
    return *reinterpret_cast<unsigned*>(&h);
}

// ---------------------------------------------------------------------------
// Fused precompute + histogram (one grid, three block ranges):
//   [0, XCVT)           : x -> bf16 table
//   [XCVT, XCVT+64)     : uW2b = b2 + u@W2_u (exact f32)
//   [XCVT+64, ...)      : dst histogram (cnt pre-zeroed by memset)
// ---------------------------------------------------------------------------
__global__ __launch_bounds__(256) void k_pre(const float* __restrict__ x,
                                             unsigned* __restrict__ xb32,
                                             const float* __restrict__ u,
                                             const float* __restrict__ W2,
                                             const float* __restrict__ b2,
                                             float* __restrict__ uW2b,
                                             const int* __restrict__ ei,
                                             int* __restrict__ cnt) {
    if (blockIdx.x >= XCVT_BLOCKS + UW2_BLOCKS) {  // histogram part
        const int e = (blockIdx.x - XCVT_BLOCKS - UW2_BLOCKS) * 256 + threadIdx.x;
        if (e < NE) atomicAdd(&cnt[ei[e]], 1);
        return;
    }
    if (blockIdx.x >= XCVT_BLOCKS) {  // uW2b part
        const int lane = threadIdx.x & 63;
        float wcol[FG];
#pragma unroll
        for (int k = 0; k < FG; ++k) wcol[k] = W2[(FN + OD + k) * OD + lane];
        const float bias = b2[lane];
        int g = ((blockIdx.x - XCVT_BLOCKS) * 256 + threadIdx.x) >> 6;
        g = __builtin_amdgcn_readfirstlane(g);
        if (g >= NG) return;
        const float* __restrict__ urow = u + (size_t)g * FG;
        float acc = bias;
#pragma unroll
        for (int k = 0; k < FG; ++k) acc = fmaf(urow[k], wcol[k], acc);
        uW2b[(size_t)g * OD + lane] = acc;
        return;
    }
    const int i = blockIdx.x * 256 + threadIdx.x;
    if (i >= NN * FN / 8) return;
    const float4* p = (const float4*)(x + (size_t)i * 8);
    float4 f0 = p[0], f1 = p[1];
    uint4 o;
    o.x = pack_bf16(f0.x, f0.y);
    o.y = pack_bf16(f0.z, f0.w);
    o.z = pack_bf16(f1.x, f1.y);
    o.w = pack_bf16(f1.z, f1.w);
    ((uint4*)xb32)[i] = o;
}

// ---------------------------------------------------------------------------
// Scan step 1 (unpadded counts): block-local exclusive + block sums.
// 196 blocks — wide and cheap (r14's single-block variant was a 112 us trap).
// ---------------------------------------------------------------------------
__global__ __launch_bounds__(SCAN_B) void k_scan1(const int* __restrict__ cnt,
                                                  int* __restrict__ start,
                                                  int* __restrict__ bsum) {
    __shared__ int lds[SCAN_B];
    const int i = blockIdx.x * SCAN_B + threadIdx.x;
    const int v = (i < NN) ? cnt[i] : 0;
    lds[threadIdx.x] = v;
    __syncthreads();
#pragma unroll
    for (int off = 1; off < SCAN_B; off <<= 1) {
        int t = (threadIdx.x >= off) ? lds[threadIdx.x - off] : 0;
        __syncthreads();
        lds[threadIdx.x] += t;
        __syncthreads();
    }
    const int incl = lds[threadIdx.x];
    if (i < NN) start[i] = incl - v;  // exclusive within block
    if (threadIdx.x == SCAN_B - 1) bsum[blockIdx.x] = incl;
}

// ---------------------------------------------------------------------------
// Scan steps 2+3 fused: every block re-scans block sums in LDS, finalizes
// start/cursor; start[NN] = NE.
// ---------------------------------------------------------------------------
__global__ __launch_bounds__(SCAN_B) void k_scan23(int* __restrict__ start,
                                                   const int* __restrict__ bsum,
                                                   const int* __restrict__ cnt,
                                                   int* __restrict__ cursor) {
    __shared__ int lds[SCAN_B];
    const int t = threadIdx.x;
    lds[t] = (t < NBLK) ? bsum[t] : 0;
    __syncthreads();
#pragma unroll
    for (int off = 1; off < SCAN_B; off <<= 1) {
        int tv = (t >= off) ? lds[t - off] : 0;
        __syncthreads();
        lds[t] += tv;
        __syncthreads();
    }
    const int boff = (blockIdx.x == 0) ? 0 : lds[blockIdx.x - 1];

    const int i = blockIdx.x * SCAN_B + t;
    if (i < NN) {
        const int s = start[i] + boff;
        start[i] = s;
        cursor[i] = s;
        if (i == NN - 1) start[NN] = s + cnt[i];  // == NE
    }
}

// ---------------------------------------------------------------------------
// Edge-major message computation + scatter (the ONE permutation pass).
// ei/ea loaded NONTEMPORAL (stream-once; keeps L2 for cursor/mbuf lines);
// mbuf stored NORMALLY (r13 lesson: NT stores evict the producer->consumer
// buffer from L2 and cost nodem2 ~25 us).
//   window = 16 consecutive edges; msg = relu([x_bf16[src] | ea] @ W1 + b1)
//   slot = atomic cursor[dst]; store msg row as f16 into mbuf[slot]
//   (column-permuted storage: f16 index slot*64 + c*4 + b holds col c+16b).
// Fragment layouts (mfma_f32_16x16x32_bf16), verified rounds 2-14:
//   A: row = lane&15, k = 8*(lane>>4)+i ; B: col = lane&15, same k
//   C: col = lane&15, row = (lane>>4)*4 + q
// ---------------------------------------------------------------------------
__global__ __launch_bounds__(256) void k_msgscat(const int* __restrict__ ei,
                                                 const float* __restrict__ ea,
                                                 const unsigned short* __restrict__ xb,
                                                 const float* __restrict__ W1,
                                                 const float* __restrict__ b1,
                                                 int* __restrict__ cursor,
                                                 unsigned short* __restrict__ mbuf) {
    const int l = threadIdx.x & 63;
    const int g = l >> 4;
    const int c = l & 15;

    // W1 B-fragments: wf[t][b] covers k = 32t.., cols 16b..16b+15
    short8 wf[3][4];
#pragma unroll
    for (int t = 0; t < 3; ++t)
#pragma unroll
        for (int b = 0; b < 4; ++b)
#pragma unroll
            for (int i = 0; i < 8; i += 2) {
                const int k = 32 * t + 8 * g + i;
                const unsigned p = pack_bf16(W1[k * OD + (c + 16 * b)],
                                             W1[(k + 1) * OD + (c + 16 * b)]);
                ((unsigned*)&wf[t][b])[i / 2] = p;
            }
    float bias[4];
#pragma unroll
    for (int b = 0; b < 4; ++b) bias[b] = b1[c + 16 * b];

    int wv = (blockIdx.x * blockDim.x + threadIdx.x) >> 6;
    wv = __builtin_amdgcn_readfirstlane(wv);

    for (int w = wv; w < NWIN_E; w += MS_WAVES) {
        const int e = w * 16 + c;            // this lane's edge (dup over g)
        const int dst = __builtin_nontemporal_load(&ei[e]);       // coalesced
        const int src = __builtin_nontemporal_load(&ei[NE + e]);  // coalesced
        int pos = 0;
        if (l < 16) pos = atomicAdd(&cursor[dst], 1);

        // A fragments: chunks 0,1 = x_bf16[src] (gather), chunk 2 = cvt(ea[e])
        short8 a0, a1, a2;
        {
            const uint4* xr = (const uint4*)(xb + (size_t)src * FN);
            uint4 q0 = xr[g];
            uint4 q1 = xr[4 + g];
            a0 = *(short8*)&q0;
            a1 = *(short8*)&q1;
        }
        {
            const floatv4* er = (const floatv4*)(ea + (size_t)e * FE);  // coalesced
            floatv4 e0 = __builtin_nontemporal_load(&er[2 * g]);
            floatv4 e1 = __builtin_nontemporal_load(&er[2 * g + 1]);
            uint4 q2;
            q2.x = pack_bf16(e0.x, e0.y);
            q2.y = pack_bf16(e0.z, e0.w);
            q2.z = pack_bf16(e1.x, e1.y);
            q2.w = pack_bf16(e1.z, e1.w);
            a2 = *(short8*)&q2;
        }

        f32x4 accb[4];
#pragma unroll
        for (int b = 0; b < 4; ++b) {
            f32x4 acc = {0.f, 0.f, 0.f, 0.f};
            acc = __builtin_amdgcn_mfma_f32_16x16x32_bf16(a0, wf[0][b], acc, 0, 0, 0);
            acc = __builtin_amdgcn_mfma_f32_16x16x32_bf16(a1, wf[1][b], acc, 0, 0, 0);
            acc = __builtin_amdgcn_mfma_f32_16x16x32_bf16(a2, wf[2][b], acc, 0, 0, 0);
            accb[b] = acc;
        }

        // store: row r = 4g+q belongs to edge w*16+r; its slot came from lane r
#pragma unroll
        for (int q = 0; q < 4; ++q) {
            const int pr = __shfl(pos, 4 * g + q);  // slot of edge 4g+q
            const float v0 = fmaxf(accb[0][q] + bias[0], 0.0f);
            const float v1 = fmaxf(accb[1][q] + bias[1], 0.0f);
            const float v2 = fmaxf(accb[2][q] + bias[2], 0.0f);
            const float v3 = fmaxf(accb[3][q] + bias[3], 0.0f);
            const __half2 h01 = __float22half2_rn(float2{v0, v1});
            const __half2 h23 = __float22half2_rn(float2{v2, v3});
            uint2 outv;
            outv.x = *reinterpret_cast<const unsigned*>(&h01);
            outv.y = *reinterpret_cast<const unsigned*>(&h23);
            *reinterpret_cast<uint2*>(mbuf + (size_t)pr * 64 + c * 4) = outv;
        }
    }
}

// ---------------------------------------------------------------------------
// Fused segment-reduce + node MLP (r11 verbatim):
//   wave owns 16 consecutive nodes. Lane (g,c) sums node (n0+c)'s mbuf rows
//   (dst-sorted contiguous segment) over STORED chunks, f32 accumulate, then
//   packs to bf16 A-fragments and runs the node MFMA with W2 rows permuted
//   to match storage order: stored s -> true col (s>>2) + 16*(s&3).
//   out = relu([x_bf16 | agg] @ W2[0:128] + uW2b[batch])
// ---------------------------------------------------------------------------
__global__ __launch_bounds__(256) void k_nodem2(const unsigned short* __restrict__ xb,
                                                const unsigned short* __restrict__ mbuf,
                                                const int* __restrict__ start,
                                                const int* __restrict__ bat,
                                                const float* __restrict__ uW2b,
                                                const float* __restrict__ W2,
                                                float* __restrict__ out) {
    const int l = threadIdx.x & 63;
    const int g = l >> 4;
    const int c = l & 15;

    // W2 B-fragments; t>=2 rows permuted to storage order (verified r7/r11)
    short8 wf[4][4];
#pragma unroll
    for (int t = 0; t < 4; ++t)
#pragma unroll
        for (int b = 0; b < 4; ++b)
#pragma unroll
            for (int i = 0; i < 8; i += 2) {
                const int col = c + 16 * b;
                unsigned p;
                if (t < 2) {
                    const int k = 32 * t + 8 * g + i;
                    p = pack_bf16(W2[k * OD + col], W2[(k + 1) * OD + col]);
                } else {
                    const int sc0 = 32 * (t - 2) + 8 * g + i;
                    const int sc1 = sc0 + 1;
                    const int k0 = FN + ((sc0 >> 2) + 16 * (sc0 & 3));
                    const int k1 = FN + ((sc1 >> 2) + 16 * (sc1 & 3));
                    p = pack_bf16(W2[k0 * OD + col], W2[k1 * OD + col]);
                }
                ((unsigned*)&wf[t][b])[i / 2] = p;
            }

    int wv = (blockIdx.x * blockDim.x + threadIdx.x) >> 6;
    wv = __builtin_amdgcn_readfirstlane(wv);

    for (int w = wv; w < NWIN_N; w += NODE_WAVES) {
        const int n0 = w * 16;
        const int n = n0 + c;
        const int s0 = start[n];
        const int cntn = start[n + 1] - s0;

        // wave-max segment length over the 16 nodes
        int mc = cntn;
        mc = max(mc, __shfl_xor(mc, 1));
        mc = max(mc, __shfl_xor(mc, 2));
        mc = max(mc, __shfl_xor(mc, 4));
        mc = max(mc, __shfl_xor(mc, 8));

        // segment sum in f32, stored-order chunks
        float s2v[8] = {0, 0, 0, 0, 0, 0, 0, 0};
        float s3v[8] = {0, 0, 0, 0, 0, 0, 0, 0};
        const unsigned short* rowb = mbuf + (size_t)s0 * 64 + 8 * g;
        for (int i = 0; i < mc; ++i) {
            if (i < cntn) {
                const uint4 u2 = *(const uint4*)(rowb + (size_t)i * 64);
                const uint4 u3 = *(const uint4*)(rowb + (size_t)i * 64 + 32);
                const __half2* h2 = (const __half2*)&u2;
                const __half2* h3 = (const __half2*)&u3;
#pragma unroll
                for (int j = 0; j < 4; ++j) {
                    const float2 f2 = __half22float2(h2[j]);
                    const float2 f3 = __half22float2(h3[j]);
                    s2v[2 * j]     += f2.x;
                    s2v[2 * j + 1] += f2.y;
                    s3v[2 * j]     += f3.x;
                    s3v[2 * j + 1] += f3.y;
                }
            }
        }
        uint4 qa2, qa3;
        qa2.x = pack_bf16(s2v[0], s2v[1]);
        qa2.y = pack_bf16(s2v[2], s2v[3]);
        qa2.z = pack_bf16(s2v[4], s2v[5]);
        qa2.w = pack_bf16(s2v[6], s2v[7]);
        qa3.x = pack_bf16(s3v[0], s3v[1]);
        qa3.y = pack_bf16(s3v[2], s3v[3]);
        qa3.z = pack_bf16(s3v[4], s3v[5]);
        qa3.w = pack_bf16(s3v[6], s3v[7]);

        // x A-fragments (coalesced: consecutive node rows)
        const uint4* xr = (const uint4*)(xb + (size_t)n * FN);
        uint4 qx0 = xr[g], qx1 = xr[4 + g];
        short8 a0 = *(short8*)&qx0, a1 = *(short8*)&qx1;
        short8 a2 = *(short8*)&qa2, a3 = *(short8*)&qa3;

        int bq[4];
#pragma unroll
        for (int q = 0; q < 4; ++q) bq[q] = bat[n0 + g * 4 + q];

#pragma unroll
        for (int b = 0; b < 4; ++b) {
            f32x4 acc = {0.f, 0.f, 0.f, 0.f};
            acc = __builtin_amdgcn_mfma_f32_16x16x32_bf16(a0, wf[0][b], acc, 0, 0, 0);
            acc = __builtin_amdgcn_mfma_f32_16x16x32_bf16(a1, wf[1][b], acc, 0, 0, 0);
            acc = __builtin_amdgcn_mfma_f32_16x16x32_bf16(a2, wf[2][b], acc, 0, 0, 0);
            acc = __builtin_amdgcn_mfma_f32_16x16x32_bf16(a3, wf[3][b], acc, 0, 0, 0);
#pragma unroll
            for (int q = 0; q < 4; ++q) {
                const int nn = n0 + g * 4 + q;
                const float val = acc[q] + uW2b[(size_t)bq[q] * OD + c + 16 * b];
                out[(size_t)nn * OD + c + 16 * b] = fmaxf(val, 0.0f);
            }
        }
    }
}

// ---------------------------------------------------------------------------
extern "C" void kernel_launch(void* const* d_in, const int* in_sizes, int n_in,
                              void* d_out, int out_size, void* d_ws, size_t ws_size,
                              hipStream_t stream) {
    const float* x    = (const float*)d_in[0];   // (50000, 64)
    const int*   ei   = (const int*)d_in[1];     // (2, 800000)
    const float* ea   = (const float*)d_in[2];   // (800000, 32)
    const float* u    = (const float*)d_in[3];   // (256, 32)
    const int*   bat  = (const int*)d_in[4];     // (50000,)
    const float* W1   = (const float*)d_in[5];   // (96, 64)
    const float* b1   = (const float*)d_in[6];   // (64,)
    const float* W2   = (const float*)d_in[7];   // (160, 64)
    const float* b2   = (const float*)d_in[8];   // (64,)
    float* out = (float*)d_out;                  // (50000, 64)

    // workspace layout (~110 MB; mbuf dominates)
    char* ws = (char*)d_ws;
    auto alloc = [&](size_t bytes) {
        char* p = ws;
        ws += (bytes + 255) & ~size_t(255);
        return p;
    };
    unsigned short* xb = (unsigned short*)alloc((size_t)NN * FN * 2);     // 6.4 MB
    float* uW2b    = (float*)alloc((size_t)NG * OD * sizeof(float));
    int*   cnt     = (int*)alloc((size_t)NN * sizeof(int));
    int*   start   = (int*)alloc((size_t)(NN + 1) * sizeof(int));
    int*   cursor  = (int*)alloc((size_t)NN * sizeof(int));
    int*   bsum    = (int*)alloc((size_t)NBLK * sizeof(int));
    unsigned short* mbuf = (unsigned short*)alloc((size_t)NE * OD * 2);   // 102.4 MB

    // zero histogram counters (stream-ordered before k_pre's hist blocks)
    hipMemsetAsync(cnt, 0, (size_t)NN * sizeof(int), stream);

    // fused precompute (x->bf16, uW2b) + dst histogram, one grid
    k_pre<<<dim3(PRE_BLOCKS), dim3(256), 0, stream>>>(x, (unsigned*)xb, u, W2, b2,
                                                      uW2b, ei, cnt);

    // wide two-step exclusive scan (r14's single-block scan was a 112 us trap)
    k_scan1<<<dim3(NBLK), dim3(SCAN_B), 0, stream>>>(cnt, start, bsum);
    k_scan23<<<dim3(NBLK), dim3(SCAN_B), 0, stream>>>(start, bsum, cnt, cursor);

    // the one permutation pass: edge-major MFMA messages -> dst-sorted slots
    k_msgscat<<<dim3(MS_BLOCKS), dim3(256), 0, stream>>>(ei, ea, xb, W1, b1, cursor, mbuf);

    // fused segment-reduce + node MLP
    k_nodem2<<<dim3(NODE_BLOCKS), dim3(256), 0, stream>>>(xb, mbuf, start, bat, uW2b, W2, out);
}

// Round 17
// 157.390 us; speedup vs baseline: 1.6725x; 1.0160x over previous
//
#include <hip/hip_runtime.h>
#include <hip/hip_bf16.h>
#include <hip/hip_fp16.h>

typedef __attribute__((ext_vector_type(8))) short short8;
typedef __attribute__((ext_vector_type(4))) float f32x4;
typedef __attribute__((ext_vector_type(4))) float floatv4;

// Problem constants (from reference)
constexpr int NN = 50000;   // nodes
constexpr int NE = 800000;  // edges
constexpr int FN = 64;      // node feat
constexpr int FE = 32;      // edge feat
constexpr int FG = 32;      // global feat
constexpr int OD = 64;      // out dim
constexpr int NG = 256;     // graphs

constexpr int SCAN_B = 256;
constexpr int NBLK = (NN + SCAN_B - 1) / SCAN_B;        // 196

constexpr int NWIN_E = NE / 16;                         // 50000 edge windows
constexpr int MS_BLOCKS = 2048;
constexpr int MS_WAVES  = MS_BLOCKS * 4;

constexpr int XCVT_BLOCKS = (NN * FN / 8 + 255) / 256;  // 1563
constexpr int PRE_BLOCKS  = XCVT_BLOCKS + (NG * 64) / 256;

constexpr int NWIN_N = NN / 16;                         // 3125
constexpr int NODE_BLOCKS = 782;                        // 1 window per wave
constexpr int NODE_WAVES  = NODE_BLOCKS * 4;

static __device__ __forceinline__ unsigned pack_bf16(float a, float b) {
    __hip_bfloat162 h = __float22bfloat162_rn(float2{a, b});
    return *reinterpret_cast<unsigned*>(&h);
}

// ---------------------------------------------------------------------------
// Fused precompute: x->bf16 table, uW2b = b2 + u@W2_u (exact f32), zero cnt
// (inline zeroing is free; the 800k-atomic histogram stays a SEPARATE kernel
//  — r15 measured fusing it into this grid costs ~19 us).
// ---------------------------------------------------------------------------
__global__ __launch_bounds__(256) void k_pre(const float* __restrict__ x,
                                             unsigned* __restrict__ xb32,
                                             const float* __restrict__ u,
                                             const float* __restrict__ W2,
                                             const float* __restrict__ b2,
                                             float* __restrict__ uW2b,
                                             int* __restrict__ cnt) {
    if (blockIdx.x >= XCVT_BLOCKS) {  // uW2b part
        const int lane = threadIdx.x & 63;
        float wcol[FG];
#pragma unroll
        for (int k = 0; k < FG; ++k) wcol[k] = W2[(FN + OD + k) * OD + lane];
        const float bias = b2[lane];
        int g = ((blockIdx.x - XCVT_BLOCKS) * 256 + threadIdx.x) >> 6;
        g = __builtin_amdgcn_readfirstlane(g);
        if (g >= NG) return;
        const float* __restrict__ urow = u + (size_t)g * FG;
        float acc = bias;
#pragma unroll
        for (int k = 0; k < FG; ++k) acc = fmaf(urow[k], wcol[k], acc);
        uW2b[(size_t)g * OD + lane] = acc;
        return;
    }
    const int i = blockIdx.x * 256 + threadIdx.x;
    if (i < NN) cnt[i] = 0;
    if (i >= NN * FN / 8) return;
    const float4* p = (const float4*)(x + (size_t)i * 8);
    float4 f0 = p[0], f1 = p[1];
    uint4 o;
    o.x = pack_bf16(f0.x, f0.y);
    o.y = pack_bf16(f0.z, f0.w);
    o.z = pack_bf16(f1.x, f1.y);
    o.w = pack_bf16(f1.z, f1.w);
    ((uint4*)xb32)[i] = o;
}

// ---------------------------------------------------------------------------
// Histogram of dst (separate dispatch: runs at full machine width).
// ---------------------------------------------------------------------------
__global__ __launch_bounds__(256) void k_hist(const int* __restrict__ ei,
                                              int* __restrict__ cnt) {
    const int e = blockIdx.x * blockDim.x + threadIdx.x;
    if (e < NE) atomicAdd(&cnt[ei[e]], 1);
}

// ---------------------------------------------------------------------------
// Scan step 1 (unpadded counts): block-local exclusive + block sums.
// 196 blocks — wide and cheap (r14's single-block variant was a 112 us trap).
// ---------------------------------------------------------------------------
__global__ __launch_bounds__(SCAN_B) void k_scan1(const int* __restrict__ cnt,
                                                  int* __restrict__ start,
                                                  int* __restrict__ bsum) {
    __shared__ int lds[SCAN_B];
    const int i = blockIdx.x * SCAN_B + threadIdx.x;
    const int v = (i < NN) ? cnt[i] : 0;
    lds[threadIdx.x] = v;
    __syncthreads();
#pragma unroll
    for (int off = 1; off < SCAN_B; off <<= 1) {
        int t = (threadIdx.x >= off) ? lds[threadIdx.x - off] : 0;
        __syncthreads();
        lds[threadIdx.x] += t;
        __syncthreads();
    }
    const int incl = lds[threadIdx.x];
    if (i < NN) start[i] = incl - v;  // exclusive within block
    if (threadIdx.x == SCAN_B - 1) bsum[blockIdx.x] = incl;
}

// ---------------------------------------------------------------------------
// Scan steps 2+3 fused: every block re-scans block sums in LDS, finalizes
// start/cursor; start[NN] = NE.
// ---------------------------------------------------------------------------
__global__ __launch_bounds__(SCAN_B) void k_scan23(int* __restrict__ start,
                                                   const int* __restrict__ bsum,
                                                   const int* __restrict__ cnt,
                                                   int* __restrict__ cursor) {
    __shared__ int lds[SCAN_B];
    const int t = threadIdx.x;
    lds[t] = (t < NBLK) ? bsum[t] : 0;
    __syncthreads();
#pragma unroll
    for (int off = 1; off < SCAN_B; off <<= 1) {
        int tv = (t >= off) ? lds[t - off] : 0;
        __syncthreads();
        lds[t] += tv;
        __syncthreads();
    }
    const int boff = (blockIdx.x == 0) ? 0 : lds[blockIdx.x - 1];

    const int i = blockIdx.x * SCAN_B + t;
    if (i < NN) {
        const int s = start[i] + boff;
        start[i] = s;
        cursor[i] = s;
        if (i == NN - 1) start[NN] = s + cnt[i];  // == NE
    }
}

// ---------------------------------------------------------------------------
// Edge-major message computation + scatter (the ONE permutation pass).
// ei/ea loaded NONTEMPORAL (stream-once; keeps L2 for cursor/mbuf — r15
// measured msgscat 77 -> 74 us); mbuf stored NORMALLY (r13: NT stores evict
// the producer->consumer buffer from L2 and cost nodem2 ~25 us).
//   window = 16 consecutive edges; msg = relu([x_bf16[src] | ea] @ W1 + b1)
//   slot = atomic cursor[dst]; store msg row as f16 into mbuf[slot]
//   (column-permuted storage: f16 index slot*64 + c*4 + b holds col c+16b).
// Fragment layouts (mfma_f32_16x16x32_bf16), verified rounds 2-15:
//   A: row = lane&15, k = 8*(lane>>4)+i ; B: col = lane&15, same k
//   C: col = lane&15, row = (lane>>4)*4 + q
// ---------------------------------------------------------------------------
__global__ __launch_bounds__(256) void k_msgscat(const int* __restrict__ ei,
                                                 const float* __restrict__ ea,
                                                 const unsigned short* __restrict__ xb,
                                                 const float* __restrict__ W1,
                                                 const float* __restrict__ b1,
                                                 int* __restrict__ cursor,
                                                 unsigned short* __restrict__ mbuf) {
    const int l = threadIdx.x & 63;
    const int g = l >> 4;
    const int c = l & 15;

    // W1 B-fragments: wf[t][b] covers k = 32t.., cols 16b..16b+15
    short8 wf[3][4];
#pragma unroll
    for (int t = 0; t < 3; ++t)
#pragma unroll
        for (int b = 0; b < 4; ++b)
#pragma unroll
            for (int i = 0; i < 8; i += 2) {
                const int k = 32 * t + 8 * g + i;
                const unsigned p = pack_bf16(W1[k * OD + (c + 16 * b)],
                                             W1[(k + 1) * OD + (c + 16 * b)]);
                ((unsigned*)&wf[t][b])[i / 2] = p;
            }
    float bias[4];
#pragma unroll
    for (int b = 0; b < 4; ++b) bias[b] = b1[c + 16 * b];

    int wv = (blockIdx.x * blockDim.x + threadIdx.x) >> 6;
    wv = __builtin_amdgcn_readfirstlane(wv);

    for (int w = wv; w < NWIN_E; w += MS_WAVES) {
        const int e = w * 16 + c;            // this lane's edge (dup over g)
        const int dst = __builtin_nontemporal_load(&ei[e]);       // coalesced
        const int src = __builtin_nontemporal_load(&ei[NE + e]);  // coalesced
        int pos = 0;
        if (l < 16) pos = atomicAdd(&cursor[dst], 1);

        // A fragments: chunks 0,1 = x_bf16[src] (gather), chunk 2 = cvt(ea[e])
        short8 a0, a1, a2;
        {
            const uint4* xr = (const uint4*)(xb + (size_t)src * FN);
            uint4 q0 = xr[g];
            uint4 q1 = xr[4 + g];
            a0 = *(short8*)&q0;
            a1 = *(short8*)&q1;
        }
        {
            const floatv4* er = (const floatv4*)(ea + (size_t)e * FE);  // coalesced
            floatv4 e0 = __builtin_nontemporal_load(&er[2 * g]);
            floatv4 e1 = __builtin_nontemporal_load(&er[2 * g + 1]);
            uint4 q2;
            q2.x = pack_bf16(e0.x, e0.y);
            q2.y = pack_bf16(e0.z, e0.w);
            q2.z = pack_bf16(e1.x, e1.y);
            q2.w = pack_bf16(e1.z, e1.w);
            a2 = *(short8*)&q2;
        }

        f32x4 accb[4];
#pragma unroll
        for (int b = 0; b < 4; ++b) {
            f32x4 acc = {0.f, 0.f, 0.f, 0.f};
            acc = __builtin_amdgcn_mfma_f32_16x16x32_bf16(a0, wf[0][b], acc, 0, 0, 0);
            acc = __builtin_amdgcn_mfma_f32_16x16x32_bf16(a1, wf[1][b], acc, 0, 0, 0);
            acc = __builtin_amdgcn_mfma_f32_16x16x32_bf16(a2, wf[2][b], acc, 0, 0, 0);
            accb[b] = acc;
        }

        // store: row r = 4g+q belongs to edge w*16+r; its slot came from lane r
#pragma unroll
        for (int q = 0; q < 4; ++q) {
            const int pr = __shfl(pos, 4 * g + q);  // slot of edge 4g+q
            const float v0 = fmaxf(accb[0][q] + bias[0], 0.0f);
            const float v1 = fmaxf(accb[1][q] + bias[1], 0.0f);
            const float v2 = fmaxf(accb[2][q] + bias[2], 0.0f);
            const float v3 = fmaxf(accb[3][q] + bias[3], 0.0f);
            const __half2 h01 = __float22half2_rn(float2{v0, v1});
            const __half2 h23 = __float22half2_rn(float2{v2, v3});
            uint2 outv;
            outv.x = *reinterpret_cast<const unsigned*>(&h01);
            outv.y = *reinterpret_cast<const unsigned*>(&h23);
            *reinterpret_cast<uint2*>(mbuf + (size_t)pr * 64 + c * 4) = outv;
        }
    }
}

// ---------------------------------------------------------------------------
// Fused segment-reduce + node MLP (r11 verbatim):
//   wave owns 16 consecutive nodes. Lane (g,c) sums node (n0+c)'s mbuf rows
//   (dst-sorted contiguous segment) over STORED chunks, f32 accumulate, then
//   packs to bf16 A-fragments and runs the node MFMA with W2 rows permuted
//   to match storage order: stored s -> true col (s>>2) + 16*(s&3).
//   out = relu([x_bf16 | agg] @ W2[0:128] + uW2b[batch])
// ---------------------------------------------------------------------------
__global__ __launch_bounds__(256) void k_nodem2(const unsigned short* __restrict__ xb,
                                                const unsigned short* __restrict__ mbuf,
                                                const int* __restrict__ start,
                                                const int* __restrict__ bat,
                                                const float* __restrict__ uW2b,
                                                const float* __restrict__ W2,
                                                float* __restrict__ out) {
    const int l = threadIdx.x & 63;
    const int g = l >> 4;
    const int c = l & 15;

    // W2 B-fragments; t>=2 rows permuted to storage order (verified r7/r11)
    short8 wf[4][4];
#pragma unroll
    for (int t = 0; t < 4; ++t)
#pragma unroll
        for (int b = 0; b < 4; ++b)
#pragma unroll
            for (int i = 0; i < 8; i += 2) {
                const int col = c + 16 * b;
                unsigned p;
                if (t < 2) {
                    const int k = 32 * t + 8 * g + i;
                    p = pack_bf16(W2[k * OD + col], W2[(k + 1) * OD + col]);
                } else {
                    const int sc0 = 32 * (t - 2) + 8 * g + i;
                    const int sc1 = sc0 + 1;
                    const int k0 = FN + ((sc0 >> 2) + 16 * (sc0 & 3));
                    const int k1 = FN + ((sc1 >> 2) + 16 * (sc1 & 3));
                    p = pack_bf16(W2[k0 * OD + col], W2[k1 * OD + col]);
                }
                ((unsigned*)&wf[t][b])[i / 2] = p;
            }

    int wv = (blockIdx.x * blockDim.x + threadIdx.x) >> 6;
    wv = __builtin_amdgcn_readfirstlane(wv);

    for (int w = wv; w < NWIN_N; w += NODE_WAVES) {
        const int n0 = w * 16;
        const int n = n0 + c;
        const int s0 = start[n];
        const int cntn = start[n + 1] - s0;

        // wave-max segment length over the 16 nodes
        int mc = cntn;
        mc = max(mc, __shfl_xor(mc, 1));
        mc = max(mc, __shfl_xor(mc, 2));
        mc = max(mc, __shfl_xor(mc, 4));
        mc = max(mc, __shfl_xor(mc, 8));

        // segment sum in f32, stored-order chunks
        float s2v[8] = {0, 0, 0, 0, 0, 0, 0, 0};
        float s3v[8] = {0, 0, 0, 0, 0, 0, 0, 0};
        const unsigned short* rowb = mbuf + (size_t)s0 * 64 + 8 * g;
        for (int i = 0; i < mc; ++i) {
            if (i < cntn) {
                const uint4 u2 = *(const uint4*)(rowb + (size_t)i * 64);
                const uint4 u3 = *(const uint4*)(rowb + (size_t)i * 64 + 32);
                const __half2* h2 = (const __half2*)&u2;
                const __half2* h3 = (const __half2*)&u3;
#pragma unroll
                for (int j = 0; j < 4; ++j) {
                    const float2 f2 = __half22float2(h2[j]);
                    const float2 f3 = __half22float2(h3[j]);
                    s2v[2 * j]     += f2.x;
                    s2v[2 * j + 1] += f2.y;
                    s3v[2 * j]     += f3.x;
                    s3v[2 * j + 1] += f3.y;
                }
            }
        }
        uint4 qa2, qa3;
        qa2.x = pack_bf16(s2v[0], s2v[1]);
        qa2.y = pack_bf16(s2v[2], s2v[3]);
        qa2.z = pack_bf16(s2v[4], s2v[5]);
        qa2.w = pack_bf16(s2v[6], s2v[7]);
        qa3.x = pack_bf16(s3v[0], s3v[1]);
        qa3.y = pack_bf16(s3v[2], s3v[3]);
        qa3.z = pack_bf16(s3v[4], s3v[5]);
        qa3.w = pack_bf16(s3v[6], s3v[7]);

        // x A-fragments (coalesced: consecutive node rows)
        const uint4* xr = (const uint4*)(xb + (size_t)n * FN);
        uint4 qx0 = xr[g], qx1 = xr[4 + g];
        short8 a0 = *(short8*)&qx0, a1 = *(short8*)&qx1;
        short8 a2 = *(short8*)&qa2, a3 = *(short8*)&qa3;

        int bq[4];
#pragma unroll
        for (int q = 0; q < 4; ++q) bq[q] = bat[n0 + g * 4 + q];

#pragma unroll
        for (int b = 0; b < 4; ++b) {
            f32x4 acc = {0.f, 0.f, 0.f, 0.f};
            acc = __builtin_amdgcn_mfma_f32_16x16x32_bf16(a0, wf[0][b], acc, 0, 0, 0);
            acc = __builtin_amdgcn_mfma_f32_16x16x32_bf16(a1, wf[1][b], acc, 0, 0, 0);
            acc = __builtin_amdgcn_mfma_f32_16x16x32_bf16(a2, wf[2][b], acc, 0, 0, 0);
            acc = __builtin_amdgcn_mfma_f32_16x16x32_bf16(a3, wf[3][b], acc, 0, 0, 0);
#pragma unroll
            for (int q = 0; q < 4; ++q) {
                const int nn = n0 + g * 4 + q;
                const float val = acc[q] + uW2b[(size_t)bq[q] * OD + c + 16 * b];
                out[(size_t)nn * OD + c + 16 * b] = fmaxf(val, 0.0f);
            }
        }
    }
}

// ---------------------------------------------------------------------------
extern "C" void kernel_launch(void* const* d_in, const int* in_sizes, int n_in,
                              void* d_out, int out_size, void* d_ws, size_t ws_size,
                              hipStream_t stream) {
    const float* x    = (const float*)d_in[0];   // (50000, 64)
    const int*   ei   = (const int*)d_in[1];     // (2, 800000)
    const float* ea   = (const float*)d_in[2];   // (800000, 32)
    const float* u    = (const float*)d_in[3];   // (256, 32)
    const int*   bat  = (const int*)d_in[4];     // (50000,)
    const float* W1   = (const float*)d_in[5];   // (96, 64)
    const float* b1   = (const float*)d_in[6];   // (64,)
    const float* W2   = (const float*)d_in[7];   // (160, 64)
    const float* b2   = (const float*)d_in[8];   // (64,)
    float* out = (float*)d_out;                  // (50000, 64)

    // workspace layout (~110 MB; mbuf dominates)
    char* ws = (char*)d_ws;
    auto alloc = [&](size_t bytes) {
        char* p = ws;
        ws += (bytes + 255) & ~size_t(255);
        return p;
    };
    unsigned short* xb = (unsigned short*)alloc((size_t)NN * FN * 2);     // 6.4 MB
    float* uW2b    = (float*)alloc((size_t)NG * OD * sizeof(float));
    int*   cnt     = (int*)alloc((size_t)NN * sizeof(int));
    int*   start   = (int*)alloc((size_t)(NN + 1) * sizeof(int));
    int*   cursor  = (int*)alloc((size_t)NN * sizeof(int));
    int*   bsum    = (int*)alloc((size_t)NBLK * sizeof(int));
    unsigned short* mbuf = (unsigned short*)alloc((size_t)NE * OD * 2);   // 102.4 MB

    // fused precompute (x->bf16, uW2b, inline cnt zeroing)
    k_pre<<<dim3(PRE_BLOCKS), dim3(256), 0, stream>>>(x, (unsigned*)xb, u, W2, b2, uW2b, cnt);

    // dst histogram (separate, full-width) + wide two-step exclusive scan
    k_hist<<<dim3((NE + 255) / 256), dim3(256), 0, stream>>>(ei, cnt);
    k_scan1<<<dim3(NBLK), dim3(SCAN_B), 0, stream>>>(cnt, start, bsum);
    k_scan23<<<dim3(NBLK), dim3(SCAN_B), 0, stream>>>(start, bsum, cnt, cursor);

    // the one permutation pass: edge-major MFMA messages -> dst-sorted slots
    k_msgscat<<<dim3(MS_BLOCKS), dim3(256), 0, stream>>>(ei, ea, xb, W1, b1, cursor, mbuf);

    // fused segment-reduce + node MLP
    k_nodem2<<<dim3(NODE_BLOCKS), dim3(256), 0, stream>>>(xb, mbuf, start, bat, uW2b, W2, out);
}

// Round 18
// 149.921 us; speedup vs baseline: 1.7558x; 1.0498x over previous
//
#include <hip/hip_runtime.h>
#include <hip/hip_bf16.h>
#include <hip/hip_fp16.h>

typedef __attribute__((ext_vector_type(8))) short short8;
typedef __attribute__((ext_vector_type(4))) float f32x4;

// Problem constants (from reference)
constexpr int NN = 50000;   // nodes
constexpr int NE = 800000;  // edges
constexpr int FN = 64;      // node feat
constexpr int FE = 32;      // edge feat
constexpr int FG = 32;      // global feat
constexpr int OD = 64;      // out dim
constexpr int NG = 256;     // graphs

constexpr int SCAN_B = 256;
constexpr int NBLK = (NN + SCAN_B - 1) / SCAN_B;        // 196

constexpr int NWIN_E = NE / 16;                         // 50000 edge windows
constexpr int MS_BLOCKS = 2048;
constexpr int MS_WAVES  = MS_BLOCKS * 4;

constexpr int XCVT_BLOCKS = (NN * FN / 8 + 255) / 256;  // 1563
constexpr int PRE_BLOCKS  = XCVT_BLOCKS + (NG * 64) / 256;

constexpr int NWIN_N = NN / 16;                         // 3125
constexpr int NODE_BLOCKS = 782;                        // 1 window per wave
constexpr int NODE_WAVES  = NODE_BLOCKS * 4;

static __device__ __forceinline__ unsigned pack_bf16(float a, float b) {
    __hip_bfloat162 h = __float22bfloat162_rn(float2{a, b});
    return *reinterpret_cast<unsigned*>(&h);
}

// ---------------------------------------------------------------------------
// Fused precompute: x->bf16 table, uW2b = b2 + u@W2_u (exact f32), zero cnt.
// (Histogram stays a SEPARATE kernel — r15 measured fusing it costs ~19 us.)
// ---------------------------------------------------------------------------
__global__ __launch_bounds__(256) void k_pre(const float* __restrict__ x,
                                             unsigned* __restrict__ xb32,
                                             const float* __restrict__ u,
                                             const float* __restrict__ W2,
                                             const float* __restrict__ b2,
                                             float* __restrict__ uW2b,
                                             int* __restrict__ cnt) {
    if (blockIdx.x >= XCVT_BLOCKS) {  // uW2b part
        const int lane = threadIdx.x & 63;
        float wcol[FG];
#pragma unroll
        for (int k = 0; k < FG; ++k) wcol[k] = W2[(FN + OD + k) * OD + lane];
        const float bias = b2[lane];
        int g = ((blockIdx.x - XCVT_BLOCKS) * 256 + threadIdx.x) >> 6;
        g = __builtin_amdgcn_readfirstlane(g);
        if (g >= NG) return;
        const float* __restrict__ urow = u + (size_t)g * FG;
        float acc = bias;
#pragma unroll
        for (int k = 0; k < FG; ++k) acc = fmaf(urow[k], wcol[k], acc);
        uW2b[(size_t)g * OD + lane] = acc;
        return;
    }
    const int i = blockIdx.x * 256 + threadIdx.x;
    if (i < NN) cnt[i] = 0;
    if (i >= NN * FN / 8) return;
    const float4* p = (const float4*)(x + (size_t)i * 8);
    float4 f0 = p[0], f1 = p[1];
    uint4 o;
    o.x = pack_bf16(f0.x, f0.y);
    o.y = pack_bf16(f0.z, f0.w);
    o.z = pack_bf16(f1.x, f1.y);
    o.w = pack_bf16(f1.z, f1.w);
    ((uint4*)xb32)[i] = o;
}

// ---------------------------------------------------------------------------
// Histogram of dst (separate dispatch: runs at full machine width).
// ---------------------------------------------------------------------------
__global__ __launch_bounds__(256) void k_hist(const int* __restrict__ ei,
                                              int* __restrict__ cnt) {
    const int e = blockIdx.x * blockDim.x + threadIdx.x;
    if (e < NE) atomicAdd(&cnt[ei[e]], 1);
}

// ---------------------------------------------------------------------------
// Scan step 1 (unpadded counts): block-local exclusive + block sums.
// 196 blocks — wide and cheap (r14's single-block variant was a 112 us trap).
// ---------------------------------------------------------------------------
__global__ __launch_bounds__(SCAN_B) void k_scan1(const int* __restrict__ cnt,
                                                  int* __restrict__ start,
                                                  int* __restrict__ bsum) {
    __shared__ int lds[SCAN_B];
    const int i = blockIdx.x * SCAN_B + threadIdx.x;
    const int v = (i < NN) ? cnt[i] : 0;
    lds[threadIdx.x] = v;
    __syncthreads();
#pragma unroll
    for (int off = 1; off < SCAN_B; off <<= 1) {
        int t = (threadIdx.x >= off) ? lds[threadIdx.x - off] : 0;
        __syncthreads();
        lds[threadIdx.x] += t;
        __syncthreads();
    }
    const int incl = lds[threadIdx.x];
    if (i < NN) start[i] = incl - v;  // exclusive within block
    if (threadIdx.x == SCAN_B - 1) bsum[blockIdx.x] = incl;
}

// ---------------------------------------------------------------------------
// Scan steps 2+3 fused: every block re-scans block sums in LDS, finalizes
// start/cursor; start[NN] = NE.
// ---------------------------------------------------------------------------
__global__ __launch_bounds__(SCAN_B) void k_scan23(int* __restrict__ start,
                                                   const int* __restrict__ bsum,
                                                   const int* __restrict__ cnt,
                                                   int* __restrict__ cursor) {
    __shared__ int lds[SCAN_B];
    const int t = threadIdx.x;
    lds[t] = (t < NBLK) ? bsum[t] : 0;
    __syncthreads();
#pragma unroll
    for (int off = 1; off < SCAN_B; off <<= 1) {
        int tv = (t >= off) ? lds[t - off] : 0;
        __syncthreads();
        lds[t] += tv;
        __syncthreads();
    }
    const int boff = (blockIdx.x == 0) ? 0 : lds[blockIdx.x - 1];

    const int i = blockIdx.x * SCAN_B + t;
    if (i < NN) {
        const int s = start[i] + boff;
        start[i] = s;
        cursor[i] = s;
        if (i == NN - 1) start[NN] = s + cnt[i];  // == NE
    }
}

// ---------------------------------------------------------------------------
// Edge-major message computation + scatter (the ONE permutation pass).
// Plain loads/stores throughout: NT loads measured msgscat −3 us but total
// +10 us across three runs (r13/r15/r16); NT stores cost nodem2 ~25 us (r13).
//   window = 16 consecutive edges; msg = relu([x_bf16[src] | ea] @ W1 + b1)
//   slot = atomic cursor[dst]; store msg row as f16 into mbuf[slot]
//   (column-permuted storage: f16 index slot*64 + c*4 + b holds col c+16b).
// Fragment layouts (mfma_f32_16x16x32_bf16), verified rounds 2-16:
//   A: row = lane&15, k = 8*(lane>>4)+i ; B: col = lane&15, same k
//   C: col = lane&15, row = (lane>>4)*4 + q
// ---------------------------------------------------------------------------
__global__ __launch_bounds__(256) void k_msgscat(const int* __restrict__ ei,
                                                 const float* __restrict__ ea,
                                                 const unsigned short* __restrict__ xb,
                                                 const float* __restrict__ W1,
                                                 const float* __restrict__ b1,
                                                 int* __restrict__ cursor,
                                                 unsigned short* __restrict__ mbuf) {
    const int l = threadIdx.x & 63;
    const int g = l >> 4;
    const int c = l & 15;

    // W1 B-fragments: wf[t][b] covers k = 32t.., cols 16b..16b+15
    short8 wf[3][4];
#pragma unroll
    for (int t = 0; t < 3; ++t)
#pragma unroll
        for (int b = 0; b < 4; ++b)
#pragma unroll
            for (int i = 0; i < 8; i += 2) {
                const int k = 32 * t + 8 * g + i;
                const unsigned p = pack_bf16(W1[k * OD + (c + 16 * b)],
                                             W1[(k + 1) * OD + (c + 16 * b)]);
                ((unsigned*)&wf[t][b])[i / 2] = p;
            }
    float bias[4];
#pragma unroll
    for (int b = 0; b < 4; ++b) bias[b] = b1[c + 16 * b];

    int wv = (blockIdx.x * blockDim.x + threadIdx.x) >> 6;
    wv = __builtin_amdgcn_readfirstlane(wv);

    for (int w = wv; w < NWIN_E; w += MS_WAVES) {
        const int e = w * 16 + c;            // this lane's edge (dup over g)
        const int dst = ei[e];               // coalesced
        const int src = ei[NE + e];          // coalesced
        int pos = 0;
        if (l < 16) pos = atomicAdd(&cursor[dst], 1);

        // A fragments: chunks 0,1 = x_bf16[src] (gather), chunk 2 = cvt(ea[e])
        short8 a0, a1, a2;
        {
            const uint4* xr = (const uint4*)(xb + (size_t)src * FN);
            uint4 q0 = xr[g];
            uint4 q1 = xr[4 + g];
            a0 = *(short8*)&q0;
            a1 = *(short8*)&q1;
        }
        {
            const float4* er = (const float4*)(ea + (size_t)e * FE);  // coalesced
            float4 e0 = er[2 * g], e1 = er[2 * g + 1];
            uint4 q2;
            q2.x = pack_bf16(e0.x, e0.y);
            q2.y = pack_bf16(e0.z, e0.w);
            q2.z = pack_bf16(e1.x, e1.y);
            q2.w = pack_bf16(e1.z, e1.w);
            a2 = *(short8*)&q2;
        }

        f32x4 accb[4];
#pragma unroll
        for (int b = 0; b < 4; ++b) {
            f32x4 acc = {0.f, 0.f, 0.f, 0.f};
            acc = __builtin_amdgcn_mfma_f32_16x16x32_bf16(a0, wf[0][b], acc, 0, 0, 0);
            acc = __builtin_amdgcn_mfma_f32_16x16x32_bf16(a1, wf[1][b], acc, 0, 0, 0);
            acc = __builtin_amdgcn_mfma_f32_16x16x32_bf16(a2, wf[2][b], acc, 0, 0, 0);
            accb[b] = acc;
        }

        // store: row r = 4g+q belongs to edge w*16+r; its slot came from lane r
#pragma unroll
        for (int q = 0; q < 4; ++q) {
            const int pr = __shfl(pos, 4 * g + q);  // slot of edge 4g+q
            const float v0 = fmaxf(accb[0][q] + bias[0], 0.0f);
            const float v1 = fmaxf(accb[1][q] + bias[1], 0.0f);
            const float v2 = fmaxf(accb[2][q] + bias[2], 0.0f);
            const float v3 = fmaxf(accb[3][q] + bias[3], 0.0f);
            const __half2 h01 = __float22half2_rn(float2{v0, v1});
            const __half2 h23 = __float22half2_rn(float2{v2, v3});
            uint2 outv;
            outv.x = *reinterpret_cast<const unsigned*>(&h01);
            outv.y = *reinterpret_cast<const unsigned*>(&h23);
            *reinterpret_cast<uint2*>(mbuf + (size_t)pr * 64 + c * 4) = outv;
        }
    }
}

// ---------------------------------------------------------------------------
// Fused segment-reduce + node MLP:
//   wave owns 16 consecutive nodes. Lane (g,c) sums node (n0+c)'s mbuf rows
//   (dst-sorted contiguous segment) over STORED chunks, f32 accumulate, then
//   packs to bf16 A-fragments and runs the node MFMA with W2 rows permuted
//   to match storage order: stored s -> true col (s>>2) + 16*(s&3).
//   out = relu([x_bf16 | agg] @ W2[0:128] + uW2b[batch])
// ---------------------------------------------------------------------------
__global__ __launch_bounds__(256) void k_nodem2(const unsigned short* __restrict__ xb,
                                                const unsigned short* __restrict__ mbuf,
                                                const int* __restrict__ start,
                                                const int* __restrict__ bat,
                                                const float* __restrict__ uW2b,
                                                const float* __restrict__ W2,
                                                float* __restrict__ out) {
    const int l = threadIdx.x & 63;
    const int g = l >> 4;
    const int c = l & 15;

    // W2 B-fragments; t>=2 rows permuted to storage order (verified r7/r11)
    short8 wf[4][4];
#pragma unroll
    for (int t = 0; t < 4; ++t)
#pragma unroll
        for (int b = 0; b < 4; ++b)
#pragma unroll
            for (int i = 0; i < 8; i += 2) {
                const int col = c + 16 * b;
                unsigned p;
                if (t < 2) {
                    const int k = 32 * t + 8 * g + i;
                    p = pack_bf16(W2[k * OD + col], W2[(k + 1) * OD + col]);
                } else {
                    const int sc0 = 32 * (t - 2) + 8 * g + i;
                    const int sc1 = sc0 + 1;
                    const int k0 = FN + ((sc0 >> 2) + 16 * (sc0 & 3));
                    const int k1 = FN + ((sc1 >> 2) + 16 * (sc1 & 3));
                    p = pack_bf16(W2[k0 * OD + col], W2[k1 * OD + col]);
                }
                ((unsigned*)&wf[t][b])[i / 2] = p;
            }

    int wv = (blockIdx.x * blockDim.x + threadIdx.x) >> 6;
    wv = __builtin_amdgcn_readfirstlane(wv);

    for (int w = wv; w < NWIN_N; w += NODE_WAVES) {
        const int n0 = w * 16;
        const int n = n0 + c;
        const int s0 = start[n];
        const int cntn = start[n + 1] - s0;

        // wave-max segment length over the 16 nodes
        int mc = cntn;
        mc = max(mc, __shfl_xor(mc, 1));
        mc = max(mc, __shfl_xor(mc, 2));
        mc = max(mc, __shfl_xor(mc, 4));
        mc = max(mc, __shfl_xor(mc, 8));

        // segment sum in f32, stored-order chunks
        float s2v[8] = {0, 0, 0, 0, 0, 0, 0, 0};
        float s3v[8] = {0, 0, 0, 0, 0, 0, 0, 0};
        const unsigned short* rowb = mbuf + (size_t)s0 * 64 + 8 * g;
        for (int i = 0; i < mc; ++i) {
            if (i < cntn) {
                const uint4 u2 = *(const uint4*)(rowb + (size_t)i * 64);
                const uint4 u3 = *(const uint4*)(rowb + (size_t)i * 64 + 32);
                const __half2* h2 = (const __half2*)&u2;
                const __half2* h3 = (const __half2*)&u3;
#pragma unroll
                for (int j = 0; j < 4; ++j) {
                    const float2 f2 = __half22float2(h2[j]);
                    const float2 f3 = __half22float2(h3[j]);
                    s2v[2 * j]     += f2.x;
                    s2v[2 * j + 1] += f2.y;
                    s3v[2 * j]     += f3.x;
                    s3v[2 * j + 1] += f3.y;
                }
            }
        }
        uint4 qa2, qa3;
        qa2.x = pack_bf16(s2v[0], s2v[1]);
        qa2.y = pack_bf16(s2v[2], s2v[3]);
        qa2.z = pack_bf16(s2v[4], s2v[5]);
        qa2.w = pack_bf16(s2v[6], s2v[7]);
        qa3.x = pack_bf16(s3v[0], s3v[1]);
        qa3.y = pack_bf16(s3v[2], s3v[3]);
        qa3.z = pack_bf16(s3v[4], s3v[5]);
        qa3.w = pack_bf16(s3v[6], s3v[7]);

        // x A-fragments (coalesced: consecutive node rows)
        const uint4* xr = (const uint4*)(xb + (size_t)n * FN);
        uint4 qx0 = xr[g], qx1 = xr[4 + g];
        short8 a0 = *(short8*)&qx0, a1 = *(short8*)&qx1;
        short8 a2 = *(short8*)&qa2, a3 = *(short8*)&qa3;

        int bq[4];
#pragma unroll
        for (int q = 0; q < 4; ++q) bq[q] = bat[n0 + g * 4 + q];

#pragma unroll
        for (int b = 0; b < 4; ++b) {
            f32x4 acc = {0.f, 0.f, 0.f, 0.f};
            acc = __builtin_amdgcn_mfma_f32_16x16x32_bf16(a0, wf[0][b], acc, 0, 0, 0);
            acc = __builtin_amdgcn_mfma_f32_16x16x32_bf16(a1, wf[1][b], acc, 0, 0, 0);
            acc = __builtin_amdgcn_mfma_f32_16x16x32_bf16(a2, wf[2][b], acc, 0, 0, 0);
            acc = __builtin_amdgcn_mfma_f32_16x16x32_bf16(a3, wf[3][b], acc, 0, 0, 0);
#pragma unroll
            for (int q = 0; q < 4; ++q) {
                const int nn = n0 + g * 4 + q;
                const float val = acc[q] + uW2b[(size_t)bq[q] * OD + c + 16 * b];
                out[(size_t)nn * OD + c + 16 * b] = fmaxf(val, 0.0f);
            }
        }
    }
}

// ---------------------------------------------------------------------------
extern "C" void kernel_launch(void* const* d_in, const int* in_sizes, int n_in,
                              void* d_out, int out_size, void* d_ws, size_t ws_size,
                              hipStream_t stream) {
    const float* x    = (const float*)d_in[0];   // (50000, 64)
    const int*   ei   = (const int*)d_in[1];     // (2, 800000)
    const float* ea   = (const float*)d_in[2];   // (800000, 32)
    const float* u    = (const float*)d_in[3];   // (256, 32)
    const int*   bat  = (const int*)d_in[4];     // (50000,)
    const float* W1   = (const float*)d_in[5];   // (96, 64)
    const float* b1   = (const float*)d_in[6];   // (64,)
    const float* W2   = (const float*)d_in[7];   // (160, 64)
    const float* b2   = (const float*)d_in[8];   // (64,)
    float* out = (float*)d_out;                  // (50000, 64)

    // workspace layout (~110 MB; mbuf dominates)
    char* ws = (char*)d_ws;
    auto alloc = [&](size_t bytes) {
        char* p = ws;
        ws += (bytes + 255) & ~size_t(255);
        return p;
    };
    unsigned short* xb = (unsigned short*)alloc((size_t)NN * FN * 2);     // 6.4 MB
    float* uW2b    = (float*)alloc((size_t)NG * OD * sizeof(float));
    int*   cnt     = (int*)alloc((size_t)NN * sizeof(int));
    int*   start   = (int*)alloc((size_t)(NN + 1) * sizeof(int));
    int*   cursor  = (int*)alloc((size_t)NN * sizeof(int));
    int*   bsum    = (int*)alloc((size_t)NBLK * sizeof(int));
    unsigned short* mbuf = (unsigned short*)alloc((size_t)NE * OD * 2);   // 102.4 MB

    // fused precompute (x->bf16, uW2b, inline cnt zeroing)
    k_pre<<<dim3(PRE_BLOCKS), dim3(256), 0, stream>>>(x, (unsigned*)xb, u, W2, b2, uW2b, cnt);

    // dst histogram (separate, full-width) + wide two-step exclusive scan
    k_hist<<<dim3((NE + 255) / 256), dim3(256), 0, stream>>>(ei, cnt);
    k_scan1<<<dim3(NBLK), dim3(SCAN_B), 0, stream>>>(cnt, start, bsum);
    k_scan23<<<dim3(NBLK), dim3(SCAN_B), 0, stream>>>(start, bsum, cnt, cursor);

    // the one permutation pass: edge-major MFMA messages -> dst-sorted slots
    k_msgscat<<<dim3(MS_BLOCKS), dim3(256), 0, stream>>>(ei, ea, xb, W1, b1, cursor, mbuf);

    // fused segment-reduce + node MLP
    k_nodem2<<<dim3(NODE_BLOCKS), dim3(256), 0, stream>>>(xb, mbuf, start, bat, uW2b, W2, out);
}

// Round 19
// 149.723 us; speedup vs baseline: 1.7582x; 1.0013x over previous
//
#include <hip/hip_runtime.h>
#include <hip/hip_bf16.h>
#include <hip/hip_fp16.h>

typedef __attribute__((ext_vector_type(8))) short short8;
typedef __attribute__((ext_vector_type(4))) float f32x4;

// Problem constants (from reference)
constexpr int NN = 50000;   // nodes
constexpr int NE = 800000;  // edges
constexpr int FN = 64;      // node feat
constexpr int FE = 32;      // edge feat
constexpr int FG = 32;      // global feat
constexpr int OD = 64;      // out dim
constexpr int NG = 256;     // graphs

constexpr int SCAN_B = 256;
constexpr int NBLK = (NN + SCAN_B - 1) / SCAN_B;        // 196

constexpr int NWIN_E = NE / 16;                         // 50000 edge windows
constexpr int MS_BLOCKS = 2048;
constexpr int MS_WAVES  = MS_BLOCKS * 4;

constexpr int XCVT_BLOCKS = (NN * FN / 8 + 255) / 256;  // 1563
constexpr int PRE_BLOCKS  = XCVT_BLOCKS + (NG * 64) / 256;

constexpr int NWIN_N = NN / 16;                         // 3125
constexpr int NODE_BLOCKS = 782;                        // 1 window per wave
constexpr int NODE_WAVES  = NODE_BLOCKS * 4;

static __device__ __forceinline__ unsigned pack_bf16(float a, float b) {
    __hip_bfloat162 h = __float22bfloat162_rn(float2{a, b});
    return *reinterpret_cast<unsigned*>(&h);
}

// ---------------------------------------------------------------------------
// Fused precompute: x->bf16 table, uW2b = b2 + u@W2_u (exact f32), zero cnt.
// (Histogram stays a SEPARATE kernel — r15 measured fusing it costs ~19 us.)
// ---------------------------------------------------------------------------
__global__ __launch_bounds__(256) void k_pre(const float* __restrict__ x,
                                             unsigned* __restrict__ xb32,
                                             const float* __restrict__ u,
                                             const float* __restrict__ W2,
                                             const float* __restrict__ b2,
                                             float* __restrict__ uW2b,
                                             int* __restrict__ cnt) {
    if (blockIdx.x >= XCVT_BLOCKS) {  // uW2b part
        const int lane = threadIdx.x & 63;
        float wcol[FG];
#pragma unroll
        for (int k = 0; k < FG; ++k) wcol[k] = W2[(FN + OD + k) * OD + lane];
        const float bias = b2[lane];
        int g = ((blockIdx.x - XCVT_BLOCKS) * 256 + threadIdx.x) >> 6;
        g = __builtin_amdgcn_readfirstlane(g);
        if (g >= NG) return;
        const float* __restrict__ urow = u + (size_t)g * FG;
        float acc = bias;
#pragma unroll
        for (int k = 0; k < FG; ++k) acc = fmaf(urow[k], wcol[k], acc);
        uW2b[(size_t)g * OD + lane] = acc;
        return;
    }
    const int i = blockIdx.x * 256 + threadIdx.x;
    if (i < NN) cnt[i] = 0;
    if (i >= NN * FN / 8) return;
    const float4* p = (const float4*)(x + (size_t)i * 8);
    float4 f0 = p[0], f1 = p[1];
    uint4 o;
    o.x = pack_bf16(f0.x, f0.y);
    o.y = pack_bf16(f0.z, f0.w);
    o.z = pack_bf16(f1.x, f1.y);
    o.w = pack_bf16(f1.z, f1.w);
    ((uint4*)xb32)[i] = o;
}

// ---------------------------------------------------------------------------
// Histogram of dst (separate dispatch: runs at full machine width).
// ---------------------------------------------------------------------------
__global__ __launch_bounds__(256) void k_hist(const int* __restrict__ ei,
                                              int* __restrict__ cnt) {
    const int e = blockIdx.x * blockDim.x + threadIdx.x;
    if (e < NE) atomicAdd(&cnt[ei[e]], 1);
}

// ---------------------------------------------------------------------------
// Scan step 1 (unpadded counts): block-local exclusive + block sums.
// 196 blocks — wide and cheap (r14's single-block variant was a 112 us trap).
// ---------------------------------------------------------------------------
__global__ __launch_bounds__(SCAN_B) void k_scan1(const int* __restrict__ cnt,
                                                  int* __restrict__ start,
                                                  int* __restrict__ bsum) {
    __shared__ int lds[SCAN_B];
    const int i = blockIdx.x * SCAN_B + threadIdx.x;
    const int v = (i < NN) ? cnt[i] : 0;
    lds[threadIdx.x] = v;
    __syncthreads();
#pragma unroll
    for (int off = 1; off < SCAN_B; off <<= 1) {
        int t = (threadIdx.x >= off) ? lds[threadIdx.x - off] : 0;
        __syncthreads();
        lds[threadIdx.x] += t;
        __syncthreads();
    }
    const int incl = lds[threadIdx.x];
    if (i < NN) start[i] = incl - v;  // exclusive within block
    if (threadIdx.x == SCAN_B - 1) bsum[blockIdx.x] = incl;
}

// ---------------------------------------------------------------------------
// Scan steps 2+3 fused: every block re-scans block sums in LDS, finalizes
// start/cursor; start[NN] = NE.
// ---------------------------------------------------------------------------
__global__ __launch_bounds__(SCAN_B) void k_scan23(int* __restrict__ start,
                                                   const int* __restrict__ bsum,
                                                   const int* __restrict__ cnt,
                                                   int* __restrict__ cursor) {
    __shared__ int lds[SCAN_B];
    const int t = threadIdx.x;
    lds[t] = (t < NBLK) ? bsum[t] : 0;
    __syncthreads();
#pragma unroll
    for (int off = 1; off < SCAN_B; off <<= 1) {
        int tv = (t >= off) ? lds[t - off] : 0;
        __syncthreads();
        lds[t] += tv;
        __syncthreads();
    }
    const int boff = (blockIdx.x == 0) ? 0 : lds[blockIdx.x - 1];

    const int i = blockIdx.x * SCAN_B + t;
    if (i < NN) {
        const int s = start[i] + boff;
        start[i] = s;
        cursor[i] = s;
        if (i == NN - 1) start[NN] = s + cnt[i];  // == NE
    }
}

// ---------------------------------------------------------------------------
// Edge-major message computation + scatter (the ONE permutation pass).
// Plain loads/stores throughout: NT loads measured msgscat −3 us but total
// +10 us across three runs (r13/r15/r16); NT stores cost nodem2 ~25 us (r13).
//   window = 16 consecutive edges; msg = relu([x_bf16[src] | ea] @ W1 + b1)
//   slot = atomic cursor[dst]; store msg row as f16 into mbuf[slot]
//   (column-permuted storage: f16 index slot*64 + c*4 + b holds col c+16b).
// Fragment layouts (mfma_f32_16x16x32_bf16), verified rounds 2-16:
//   A: row = lane&15, k = 8*(lane>>4)+i ; B: col = lane&15, same k
//   C: col = lane&15, row = (lane>>4)*4 + q
// ---------------------------------------------------------------------------
__global__ __launch_bounds__(256) void k_msgscat(const int* __restrict__ ei,
                                                 const float* __restrict__ ea,
                                                 const unsigned short* __restrict__ xb,
                                                 const float* __restrict__ W1,
                                                 const float* __restrict__ b1,
                                                 int* __restrict__ cursor,
                                                 unsigned short* __restrict__ mbuf) {
    const int l = threadIdx.x & 63;
    const int g = l >> 4;
    const int c = l & 15;

    // W1 B-fragments: wf[t][b] covers k = 32t.., cols 16b..16b+15
    short8 wf[3][4];
#pragma unroll
    for (int t = 0; t < 3; ++t)
#pragma unroll
        for (int b = 0; b < 4; ++b)
#pragma unroll
            for (int i = 0; i < 8; i += 2) {
                const int k = 32 * t + 8 * g + i;
                const unsigned p = pack_bf16(W1[k * OD + (c + 16 * b)],
                                             W1[(k + 1) * OD + (c + 16 * b)]);
                ((unsigned*)&wf[t][b])[i / 2] = p;
            }
    float bias[4];
#pragma unroll
    for (int b = 0; b < 4; ++b) bias[b] = b1[c + 16 * b];

    int wv = (blockIdx.x * blockDim.x + threadIdx.x) >> 6;
    wv = __builtin_amdgcn_readfirstlane(wv);

    for (int w = wv; w < NWIN_E; w += MS_WAVES) {
        const int e = w * 16 + c;            // this lane's edge (dup over g)
        const int dst = ei[e];               // coalesced
        const int src = ei[NE + e];          // coalesced
        int pos = 0;
        if (l < 16) pos = atomicAdd(&cursor[dst], 1);

        // A fragments: chunks 0,1 = x_bf16[src] (gather), chunk 2 = cvt(ea[e])
        short8 a0, a1, a2;
        {
            const uint4* xr = (const uint4*)(xb + (size_t)src * FN);
            uint4 q0 = xr[g];
            uint4 q1 = xr[4 + g];
            a0 = *(short8*)&q0;
            a1 = *(short8*)&q1;
        }
        {
            const float4* er = (const float4*)(ea + (size_t)e * FE);  // coalesced
            float4 e0 = er[2 * g], e1 = er[2 * g + 1];
            uint4 q2;
            q2.x = pack_bf16(e0.x, e0.y);
            q2.y = pack_bf16(e0.z, e0.w);
            q2.z = pack_bf16(e1.x, e1.y);
            q2.w = pack_bf16(e1.z, e1.w);
            a2 = *(short8*)&q2;
        }

        f32x4 accb[4];
#pragma unroll
        for (int b = 0; b < 4; ++b) {
            f32x4 acc = {0.f, 0.f, 0.f, 0.f};
            acc = __builtin_amdgcn_mfma_f32_16x16x32_bf16(a0, wf[0][b], acc, 0, 0, 0);
            acc = __builtin_amdgcn_mfma_f32_16x16x32_bf16(a1, wf[1][b], acc, 0, 0, 0);
            acc = __builtin_amdgcn_mfma_f32_16x16x32_bf16(a2, wf[2][b], acc, 0, 0, 0);
            accb[b] = acc;
        }

        // store: row r = 4g+q belongs to edge w*16+r; its slot came from lane r
#pragma unroll
        for (int q = 0; q < 4; ++q) {
            const int pr = __shfl(pos, 4 * g + q);  // slot of edge 4g+q
            const float v0 = fmaxf(accb[0][q] + bias[0], 0.0f);
            const float v1 = fmaxf(accb[1][q] + bias[1], 0.0f);
            const float v2 = fmaxf(accb[2][q] + bias[2], 0.0f);
            const float v3 = fmaxf(accb[3][q] + bias[3], 0.0f);
            const __half2 h01 = __float22half2_rn(float2{v0, v1});
            const __half2 h23 = __float22half2_rn(float2{v2, v3});
            uint2 outv;
            outv.x = *reinterpret_cast<const unsigned*>(&h01);
            outv.y = *reinterpret_cast<const unsigned*>(&h23);
            *reinterpret_cast<uint2*>(mbuf + (size_t)pr * 64 + c * 4) = outv;
        }
    }
}

// ---------------------------------------------------------------------------
// Fused segment-reduce + node MLP:
//   wave owns 16 consecutive nodes. Lane (g,c) sums node (n0+c)'s mbuf rows
//   (dst-sorted contiguous segment) over STORED chunks, f32 accumulate, then
//   packs to bf16 A-fragments and runs the node MFMA with W2 rows permuted
//   to match storage order: stored s -> true col (s>>2) + 16*(s&3).
//   out = relu([x_bf16 | agg] @ W2[0:128] + uW2b[batch])
// ---------------------------------------------------------------------------
__global__ __launch_bounds__(256) void k_nodem2(const unsigned short* __restrict__ xb,
                                                const unsigned short* __restrict__ mbuf,
                                                const int* __restrict__ start,
                                                const int* __restrict__ bat,
                                                const float* __restrict__ uW2b,
                                                const float* __restrict__ W2,
                                                float* __restrict__ out) {
    const int l = threadIdx.x & 63;
    const int g = l >> 4;
    const int c = l & 15;

    // W2 B-fragments; t>=2 rows permuted to storage order (verified r7/r11)
    short8 wf[4][4];
#pragma unroll
    for (int t = 0; t < 4; ++t)
#pragma unroll
        for (int b = 0; b < 4; ++b)
#pragma unroll
            for (int i = 0; i < 8; i += 2) {
                const int col = c + 16 * b;
                unsigned p;
                if (t < 2) {
                    const int k = 32 * t + 8 * g + i;
                    p = pack_bf16(W2[k * OD + col], W2[(k + 1) * OD + col]);
                } else {
                    const int sc0 = 32 * (t - 2) + 8 * g + i;
                    const int sc1 = sc0 + 1;
                    const int k0 = FN + ((sc0 >> 2) + 16 * (sc0 & 3));
                    const int k1 = FN + ((sc1 >> 2) + 16 * (sc1 & 3));
                    p = pack_bf16(W2[k0 * OD + col], W2[k1 * OD + col]);
                }
                ((unsigned*)&wf[t][b])[i / 2] = p;
            }

    int wv = (blockIdx.x * blockDim.x + threadIdx.x) >> 6;
    wv = __builtin_amdgcn_readfirstlane(wv);

    for (int w = wv; w < NWIN_N; w += NODE_WAVES) {
        const int n0 = w * 16;
        const int n = n0 + c;
        const int s0 = start[n];
        const int cntn = start[n + 1] - s0;

        // wave-max segment length over the 16 nodes
        int mc = cntn;
        mc = max(mc, __shfl_xor(mc, 1));
        mc = max(mc, __shfl_xor(mc, 2));
        mc = max(mc, __shfl_xor(mc, 4));
        mc = max(mc, __shfl_xor(mc, 8));

        // segment sum in f32, stored-order chunks
        float s2v[8] = {0, 0, 0, 0, 0, 0, 0, 0};
        float s3v[8] = {0, 0, 0, 0, 0, 0, 0, 0};
        const unsigned short* rowb = mbuf + (size_t)s0 * 64 + 8 * g;
        for (int i = 0; i < mc; ++i) {
            if (i < cntn) {
                const uint4 u2 = *(const uint4*)(rowb + (size_t)i * 64);
                const uint4 u3 = *(const uint4*)(rowb + (size_t)i * 64 + 32);
                const __half2* h2 = (const __half2*)&u2;
                const __half2* h3 = (const __half2*)&u3;
#pragma unroll
                for (int j = 0; j < 4; ++j) {
                    const float2 f2 = __half22float2(h2[j]);
                    const float2 f3 = __half22float2(h3[j]);
                    s2v[2 * j]     += f2.x;
                    s2v[2 * j + 1] += f2.y;
                    s3v[2 * j]     += f3.x;
                    s3v[2 * j + 1] += f3.y;
                }
            }
        }
        uint4 qa2, qa3;
        qa2.x = pack_bf16(s2v[0], s2v[1]);
        qa2.y = pack_bf16(s2v[2], s2v[3]);
        qa2.z = pack_bf16(s2v[4], s2v[5]);
        qa2.w = pack_bf16(s2v[6], s2v[7]);
        qa3.x = pack_bf16(s3v[0], s3v[1]);
        qa3.y = pack_bf16(s3v[2], s3v[3]);
        qa3.z = pack_bf16(s3v[4], s3v[5]);
        qa3.w = pack_bf16(s3v[6], s3v[7]);

        // x A-fragments (coalesced: consecutive node rows)
        const uint4* xr = (const uint4*)(xb + (size_t)n * FN);
        uint4 qx0 = xr[g], qx1 = xr[4 + g];
        short8 a0 = *(short8*)&qx0, a1 = *(short8*)&qx1;
        short8 a2 = *(short8*)&qa2, a3 = *(short8*)&qa3;

        int bq[4];
#pragma unroll
        for (int q = 0; q < 4; ++q) bq[q] = bat[n0 + g * 4 + q];

#pragma unroll
        for (int b = 0; b < 4; ++b) {
            f32x4 acc = {0.f, 0.f, 0.f, 0.f};
            acc = __builtin_amdgcn_mfma_f32_16x16x32_bf16(a0, wf[0][b], acc, 0, 0, 0);
            acc = __builtin_amdgcn_mfma_f32_16x16x32_bf16(a1, wf[1][b], acc, 0, 0, 0);
            acc = __builtin_amdgcn_mfma_f32_16x16x32_bf16(a2, wf[2][b], acc, 0, 0, 0);
            acc = __builtin_amdgcn_mfma_f32_16x16x32_bf16(a3, wf[3][b], acc, 0, 0, 0);
#pragma unroll
            for (int q = 0; q < 4; ++q) {
                const int nn = n0 + g * 4 + q;
                const float val = acc[q] + uW2b[(size_t)bq[q] * OD + c + 16 * b];
                out[(size_t)nn * OD + c + 16 * b] = fmaxf(val, 0.0f);
            }
        }
    }
}

// ---------------------------------------------------------------------------
extern "C" void kernel_launch(void* const* d_in, const int* in_sizes, int n_in,
                              void* d_out, int out_size, void* d_ws, size_t ws_size,
                              hipStream_t stream) {
    const float* x    = (const float*)d_in[0];   // (50000, 64)
    const int*   ei   = (const int*)d_in[1];     // (2, 800000)
    const float* ea   = (const float*)d_in[2];   // (800000, 32)
    const float* u    = (const float*)d_in[3];   // (256, 32)
    const int*   bat  = (const int*)d_in[4];     // (50000,)
    const float* W1   = (const float*)d_in[5];   // (96, 64)
    const float* b1   = (const float*)d_in[6];   // (64,)
    const float* W2   = (const float*)d_in[7];   // (160, 64)
    const float* b2   = (const float*)d_in[8];   // (64,)
    float* out = (float*)d_out;                  // (50000, 64)

    // workspace layout (~110 MB; mbuf dominates)
    char* ws = (char*)d_ws;
    auto alloc = [&](size_t bytes) {
        char* p = ws;
        ws += (bytes + 255) & ~size_t(255);
        return p;
    };
    unsigned short* xb = (unsigned short*)alloc((size_t)NN * FN * 2);     // 6.4 MB
    float* uW2b    = (float*)alloc((size_t)NG * OD * sizeof(float));
    int*   cnt     = (int*)alloc((size_t)NN * sizeof(int));
    int*   start   = (int*)alloc((size_t)(NN + 1) * sizeof(int));
    int*   cursor  = (int*)alloc((size_t)NN * sizeof(int));
    int*   bsum    = (int*)alloc((size_t)NBLK * sizeof(int));
    unsigned short* mbuf = (unsigned short*)alloc((size_t)NE * OD * 2);   // 102.4 MB

    // fused precompute (x->bf16, uW2b, inline cnt zeroing)
    k_pre<<<dim3(PRE_BLOCKS), dim3(256), 0, stream>>>(x, (unsigned*)xb, u, W2, b2, uW2b, cnt);

    // dst histogram (separate, full-width) + wide two-step exclusive scan
    k_hist<<<dim3((NE + 255) / 256), dim3(256), 0, stream>>>(ei, cnt);
    k_scan1<<<dim3(NBLK), dim3(SCAN_B), 0, stream>>>(cnt, start, bsum);
    k_scan23<<<dim3(NBLK), dim3(SCAN_B), 0, stream>>>(start, bsum, cnt, cursor);

    // the one permutation pass: edge-major MFMA messages -> dst-sorted slots
    k_msgscat<<<dim3(MS_BLOCKS), dim3(256), 0, stream>>>(ei, ea, xb, W1, b1, cursor, mbuf);

    // fused segment-reduce + node MLP
    k_nodem2<<<dim3(NODE_BLOCKS), dim3(256), 0, stream>>>(xb, mbuf, start, bat, uW2b, W2, out);
}